// Round 6
// baseline (41708.347 us; speedup 1.0000x reference)
//
#include <hip/hip_runtime.h>
#include <cstdint>
#include <cstddef>

// ---------------- types ----------------
typedef __bf16 bf16;
typedef __bf16 bf16x8 __attribute__((ext_vector_type(8)));
typedef float  f32x4  __attribute__((ext_vector_type(4)));
typedef unsigned int uint2v __attribute__((ext_vector_type(2)));
typedef unsigned int uint4v __attribute__((ext_vector_type(4)));
typedef unsigned long long u64;

// ---------------- problem sizes ----------------
constexpr int B_=256, T_=512, H_=512, X_=128, S_=64, IN0=192;
constexpr int NG=2;              // batch groups
constexpr int MG=128;            // rows per group
constexpr int WPG=128;           // workgroups per group (slices)
constexpr int KB_X=4, KB_H=16, KB_S=2;

// ---------------- ws layout ----------------
constexpr size_t OFF_FLG=0;                           // 2*128*64 = 16384 B
constexpr size_t OFF_BC =16384;                       // 2*64 B (pad to 32768)
constexpr size_t OFF_SC =32768;                       // [2][NG][64][128] f32 = 131072 B
constexpr size_t OFF_HP =OFF_SC+2ull*NG*64*128*4;     // 4 planes: H0H,H0L,H1H,H1L
constexpr size_t PLANE  =2ull*B_*H_*2;                // 524288 B each (double buffered)
constexpr size_t WS_NEED=OFF_HP+4*PLANE;              // ~2.3 MB

// ---------------- LDS ----------------
constexpr int NWX=KB_X*512;
constexpr int NWH=KB_H*512;
constexpr int NWS=KB_S*512;
constexpr int SMEM_BYTES = (2*NWX + 8*NWH + 2*NWS)*2
                         + 512*4 + 128*17*4 + 512*2*2 + 32*4;
static_assert(SMEM_BYTES == 156288, "lds size");
static_assert(SMEM_BYTES <= 160*1024, "lds limit");

// ---------------- coherent (agent-scope, L2-bypass) access ----------------
__device__ __forceinline__ u64 AL(const u64* p) {
  return __hip_atomic_load(p, __ATOMIC_RELAXED, __HIP_MEMORY_SCOPE_AGENT);
}
__device__ __forceinline__ bf16x8 MK(const u64 q[2]) {
  union { u64 q[2]; bf16x8 v; } u;
  u.q[0] = q[0]; u.q[1] = q[1];
  return u.v;
}
__device__ __forceinline__ void astore8(bf16* p, uint2v v) {
  union { uint2v v; u64 q; } u; u.v = v;
  __hip_atomic_store((u64*)p, u.q, __ATOMIC_RELAXED, __HIP_MEMORY_SCOPE_AGENT);
}
__device__ __forceinline__ void astoref(float* p, float v) {
  __hip_atomic_store((unsigned*)p, __float_as_uint(v), __ATOMIC_RELAXED, __HIP_MEMORY_SCOPE_AGENT);
}
__device__ __forceinline__ float aloadf(const float* p) {
  return __uint_as_float(__hip_atomic_load((unsigned*)p, __ATOMIC_RELAXED, __HIP_MEMORY_SCOPE_AGENT));
}

// ---------------- helpers ----------------
__device__ __forceinline__ f32x4 mfma16(bf16x8 a, bf16x8 b, f32x4 c) {
  return __builtin_amdgcn_mfma_f32_16x16x32_bf16(a, b, c, 0, 0, 0);
}
__device__ __forceinline__ f32x4 mfma3(bf16x8 ah, bf16x8 al, bf16x8 wh, bf16x8 wl, f32x4 c) {
  c = mfma16(ah, wh, c);
  c = mfma16(al, wh, c);
  c = mfma16(ah, wl, c);
  return c;
}
__device__ __forceinline__ void split8p(const float* v, bf16x8& ah, bf16x8& al) {
  #pragma unroll
  for (int i=0;i<8;++i){ float f=v[i]; bf16 h=(bf16)f; ah[i]=h; al[i]=(bf16)(f-(float)h); }
}
__device__ __forceinline__ void split8v(f32x4 v0, f32x4 v1, bf16x8& ah, bf16x8& al) {
  #pragma unroll
  for (int i=0;i<4;++i){ float f=v0[i]; bf16 h=(bf16)f; ah[i]=h; al[i]=(bf16)(f-(float)h); }
  #pragma unroll
  for (int i=0;i<4;++i){ float f=v1[i]; bf16 h=(bf16)f; ah[4+i]=h; al[4+i]=(bf16)(f-(float)h); }
}
__device__ __forceinline__ float sigm(float v) { return 1.0f / (1.0f + __expf(-v)); }
__device__ __forceinline__ float tanhr(float v) {
  v = fminf(15.0f, fmaxf(-15.0f, v));
  float e = __expf(2.0f * v);
  return (e - 1.0f) / (e + 1.0f);
}

// Fence-free group barrier (R5, unchanged)
__device__ __forceinline__ void group_barrier(int* flg, int* bc, int ns, int& phase) {
  ++phase;
  const int p = phase;
  asm volatile("s_waitcnt vmcnt(0)" ::: "memory");
  __syncthreads();
  if (threadIdx.x == 0)
    __hip_atomic_store(flg + ns*16, p, __ATOMIC_RELAXED, __HIP_MEMORY_SCOPE_AGENT);
  if (ns == 0) {
    if (threadIdx.x < WPG) {
      while (__hip_atomic_load(flg + (int)threadIdx.x*16, __ATOMIC_RELAXED,
                               __HIP_MEMORY_SCOPE_AGENT) < p)
        __builtin_amdgcn_s_sleep(1);
    }
    __syncthreads();
    if (threadIdx.x == 0)
      __hip_atomic_store(bc, p, __ATOMIC_RELAXED, __HIP_MEMORY_SCOPE_AGENT);
  }
  if (threadIdx.x == 0) {
    while (__hip_atomic_load(bc, __ATOMIC_RELAXED, __HIP_MEMORY_SCOPE_AGENT) < p)
      __builtin_amdgcn_s_sleep(1);
  }
  __syncthreads();
}

__device__ void pack_slice(bf16* dH, bf16* dL, const float* src, int stride,
                           int koff, int nkb, int ns) {
  for (int p = (int)threadIdx.x; p < nkb*64; p += 256) {
    int ln = p & 63, kb = p >> 6;
    int c = ln & 15, k = kb*32 + ((ln>>4)<<3);
    int gcol = ((c>>2)<<9) + ns*4 + (c&3);
    const float* sp = src + (size_t)gcol*stride + koff + k;
    f32x4 v0 = *(const f32x4*)sp, v1 = *(const f32x4*)(sp+4);
    bf16x8 hv, lv;
    split8v(v0, v1, hv, lv);
    *(bf16x8*)(dH + p*8) = hv;
    *(bf16x8*)(dL + p*8) = lv;
  }
}

// ---------------- zero kernel ----------------
__global__ void zero_kernel(char* __restrict__ ws) {
  size_t i = (size_t)blockIdx.x*256 + threadIdx.x;
  size_t nsync = 32768/16;
  if (i < nsync) { ((uint4v*)(ws+OFF_FLG))[i] = (uint4v){0,0,0,0}; return; }
  i -= nsync;
  if (i < 4*PLANE/16) ((uint4v*)(ws+OFF_HP))[i] = (uint4v){0,0,0,0};
}

// ---------------- persistent LSTM kernel ----------------
#define FRL(base, kb) (*(const bf16x8*)((base) + (((kb)*64 + lane)*8)))

// Batched half-chain: issue 64 8B coherent loads (2 mt x 8 kb x 2 planes),
// then consume with MFMAs. DUAL adds a second accumulator/weight pair.
template<bool DUAL>
__device__ __forceinline__ void chain8(const bf16* pH, const bf16* pL,
    const bf16* sWH, const bf16* sWL, const bf16* sW2H, const bf16* sW2L,
    int lane, const int* rowA, int kq, int kb0, f32x4* accA, f32x4* accB)
{
  u64 qh[2][8][2], ql[2][8][2];
  #pragma unroll
  for (int mt=0;mt<2;++mt) {
    const u64* bH = (const u64*)(pH + (size_t)rowA[mt]*H_ + kq) + (size_t)kb0*8;
    const u64* bL = (const u64*)(pL + (size_t)rowA[mt]*H_ + kq) + (size_t)kb0*8;
    #pragma unroll
    for (int k=0;k<8;++k) {
      qh[mt][k][0] = AL(bH + k*8);
      qh[mt][k][1] = AL(bH + k*8 + 1);
      ql[mt][k][0] = AL(bL + k*8);
      ql[mt][k][1] = AL(bL + k*8 + 1);
    }
  }
  #pragma unroll
  for (int k=0;k<8;++k) {
    const int kb = kb0 + k;
    bf16x8 wh = FRL(sWH,kb), wl = FRL(sWL,kb);
    #pragma unroll
    for (int mt=0;mt<2;++mt) {
      bf16x8 ah = MK(qh[mt][k]), al2 = MK(ql[mt][k]);
      accA[mt] = mfma3(ah, al2, wh, wl, accA[mt]);
      if (DUAL) {
        bf16x8 w2h = FRL(sW2H,kb), w2l = FRL(sW2L,kb);
        accB[mt] = mfma3(ah, al2, w2h, w2l, accB[mt]);
      }
    }
  }
}

__global__ void __launch_bounds__(256, 1)
lstm_kernel(const float* __restrict__ x, const float* __restrict__ s0,
            const float* __restrict__ Wi0, const float* __restrict__ Wh0g,
            const float* __restrict__ bi0, const float* __restrict__ bh0,
            const float* __restrict__ Wi1g, const float* __restrict__ Wh1g,
            const float* __restrict__ bi1, const float* __restrict__ bh1,
            const float* __restrict__ Wfc, const float* __restrict__ bfc,
            float* __restrict__ out, char* __restrict__ ws)
{
  const int bid = blockIdx.x;
  const int g = bid & 1, ns = bid >> 1;
  const int tid = threadIdx.x;
  const int w = tid >> 6, lane = tid & 63, l15 = lane & 15;
  const int kq = (lane >> 4) << 3;
  const int mB = g * MG;
  int rowA[2];
  rowA[0] = mB + (w*2)*16 + l15;
  rowA[1] = rowA[0] + 16;

  int* flg = (int*)(ws + OFF_FLG) + g*128*16;
  int* bc  = (int*)(ws + OFF_BC) + g*16;
  float* SCbase = (float*)(ws + OFF_SC);
  bf16* H0H_ = (bf16*)(ws + OFF_HP);
  bf16* H0L_ = (bf16*)(ws + OFF_HP + PLANE);
  bf16* H1H_ = (bf16*)(ws + OFF_HP + 2*PLANE);
  bf16* H1L_ = (bf16*)(ws + OFF_HP + 3*PLANE);

  extern __shared__ char smem[];
  bf16* sWxH  = (bf16*)smem;
  bf16* sWxL  = sWxH + NWX;
  bf16* sWh0H = sWxL + NWX;
  bf16* sWh0L = sWh0H + NWH;
  bf16* sWcbH = sWh0L + NWH;
  bf16* sWcbL = sWcbH + NWH;
  bf16* sWi1H = sWcbL + NWH;
  bf16* sWi1L = sWi1H + NWH;
  bf16* sWh1H = sWi1L + NWH;
  bf16* sWh1L = sWh1H + NWH;
  bf16* sWsH  = sWh1L + NWH;
  bf16* sWsL  = sWsH + NWS;
  float* sWfc = (float*)(sWsL + NWS);
  float* sG   = sWfc + 512;
  bf16*  sHh  = (bf16*)(sG + 128*17);
  bf16*  sHl  = sHh + 512;
  float* sB0  = (float*)(sHl + 512);
  float* sB1  = sB0 + 16;

  // ---- in-kernel weight packing (hi/lo bf16 pairs) ----
  pack_slice(sWxH,  sWxL,  Wi0,  IN0, 0,  KB_X, ns);
  pack_slice(sWh0H, sWh0L, Wh0g, H_,  0,  KB_H, ns);
  pack_slice(sWi1H, sWi1L, Wi1g, H_,  0,  KB_H, ns);
  pack_slice(sWh1H, sWh1L, Wh1g, H_,  0,  KB_H, ns);
  pack_slice(sWsH,  sWsL,  Wi0,  IN0, X_, KB_S, ns);
  for (int p = tid; p < KB_H*64; p += 256) {
    int ln = p & 63, kb = p >> 6;
    int c = ln & 15, k = kb*32 + ((ln>>4)<<3);
    int gcol = ((c>>2)<<9) + ns*4 + (c&3);
    const float* wis = Wi0 + (size_t)gcol*IN0 + X_;
    float a[8] = {0,0,0,0,0,0,0,0};
    for (int o = 0; o < S_; ++o) {
      float wv = wis[o];
      const float* fr = Wfc + (size_t)o*H_ + k;
      f32x4 f0 = *(const f32x4*)fr, f1 = *(const f32x4*)(fr+4);
      a[0]+=wv*f0[0]; a[1]+=wv*f0[1]; a[2]+=wv*f0[2]; a[3]+=wv*f0[3];
      a[4]+=wv*f1[0]; a[5]+=wv*f1[1]; a[6]+=wv*f1[2]; a[7]+=wv*f1[3];
    }
    bf16x8 hv, lv;
    split8p(a, hv, lv);
    *(bf16x8*)(sWcbH + p*8) = hv;
    *(bf16x8*)(sWcbL + p*8) = lv;
  }
  for (int j = tid; j < H_; j += 256) sWfc[j] = Wfc[(size_t)(ns>>1)*H_ + j];
  if (tid < 16) {
    int gcol = ((tid>>2)<<9) + ns*4 + (tid&3);
    sB0[tid] = bi0[gcol] + bh0[gcol];
    sB1[tid] = bi1[gcol] + bh1[gcol];
  }

  float bfcW;
  {
    int gcol = ((l15>>2)<<9) + ns*4 + (l15&3);
    const float* wr = Wi0 + (size_t)gcol*IN0 + X_;
    float bw = 0.f;
    for (int o = 0; o < S_; ++o) bw += bfc[o]*wr[o];
    bfcW = bw;
  }
  const float bfc_ns = bfc[ns>>1];

  float s_reg[2][16];
  #pragma unroll
  for (int mt=0;mt<2;++mt)
    #pragma unroll
    for (int kb=0;kb<KB_S;++kb)
      #pragma unroll
      for (int i=0;i<8;++i)
        s_reg[mt][kb*8+i] = s0[(size_t)rowA[mt]*S_ + kb*32 + kq + i];

  __syncthreads();

  f32x4 Gs[2];
  #pragma unroll
  for (int mt=0;mt<2;++mt) {
    bf16x8 sh0,sl0,sh1,sl1;
    split8p(&s_reg[mt][0], sh0, sl0);
    split8p(&s_reg[mt][8], sh1, sl1);
    f32x4 a = (f32x4){0.f,0.f,0.f,0.f};
    a = mfma3(sh0, sl0, FRL(sWsH,0), FRL(sWsL,0), a);
    a = mfma3(sh1, sl1, FRL(sWsH,1), FRL(sWsL,1), a);
    Gs[mt] = a;
  }

  float c0s[2] = {0.f,0.f}, c1s[2] = {0.f,0.f};
  const int crow = tid >> 1;
  const int dbase = (tid & 1) << 1;
  const int frow = tid >> 1, fhalf = tid & 1;
  int phase = 0;

  for (int t = 0; t < T_; ++t) {
    const int rd = t & 1, wr = rd ^ 1;
    const size_t rdo = (size_t)rd*B_*H_, wro = (size_t)wr*B_*H_;
    float* SCp = SCbase + ((size_t)rd*NG + g)*(64*128);

    // ---- fc (fp32, even slices): out(t-1)[:, ns>>1] -- batched loads ----
    if (t > 0 && (ns & 1) == 0) {
      const bf16* hH = H1H_ + rdo + (size_t)(mB+frow)*H_ + fhalf*256;
      const bf16* hL = H1L_ + rdo + (size_t)(mB+frow)*H_ + fhalf*256;
      const float* wp = sWfc + fhalf*256;
      float a = 0.f;
      #pragma unroll
      for (int half = 0; half < 2; ++half) {
        u64 qh[16][2], ql[16][2];
        #pragma unroll
        for (int c2 = 0; c2 < 16; ++c2) {
          const u64* ph = (const u64*)(hH + half*128 + c2*8);
          const u64* pl = (const u64*)(hL + half*128 + c2*8);
          qh[c2][0] = AL(ph); qh[c2][1] = AL(ph+1);
          ql[c2][0] = AL(pl); ql[c2][1] = AL(pl+1);
        }
        #pragma unroll
        for (int c2 = 0; c2 < 16; ++c2) {
          bf16x8 hv = MK(qh[c2]), lv = MK(ql[c2]);
          const float* w2 = wp + half*128 + c2*8;
          f32x4 w0 = *(const f32x4*)w2, w1 = *(const f32x4*)(w2+4);
          a += ((float)hv[0]+(float)lv[0])*w0[0] + ((float)hv[1]+(float)lv[1])*w0[1]
             + ((float)hv[2]+(float)lv[2])*w0[2] + ((float)hv[3]+(float)lv[3])*w0[3]
             + ((float)hv[4]+(float)lv[4])*w1[0] + ((float)hv[5]+(float)lv[5])*w1[1]
             + ((float)hv[6]+(float)lv[6])*w1[2] + ((float)hv[7]+(float)lv[7])*w1[3];
        }
      }
      a += __shfl_xor(a, 1);
      if (fhalf == 0) {
        float o = a + bfc_ns;
        out[((size_t)(mB+frow)*T_ + (t-1))*S_ + (ns>>1)] = o;
        astoref(&SCp[(ns>>1)*128 + frow], o);
      }
    }

    // ---- phase-1 MFMA ----
    f32x4 acc0[2], acc1[2];
    {
      float addb = (t > 0) ? bfcW : 0.f;
      #pragma unroll
      for (int mt=0;mt<2;++mt) {
        #pragma unroll
        for (int r=0;r<4;++r) acc0[mt][r] = Gs[mt][r] + addb;
        acc1[mt] = (f32x4){0.f,0.f,0.f,0.f};
      }
    }
    #pragma unroll
    for (int kb=0; kb<KB_X; ++kb) {          // x chain (cached loads)
      bf16x8 wh = FRL(sWxH,kb), wl = FRL(sWxL,kb);
      #pragma unroll
      for (int mt=0;mt<2;++mt) {
        const float* xp = x + ((size_t)rowA[mt]*T_ + t)*X_ + kb*32 + kq;
        bf16x8 ah, al2;
        split8v(*(const f32x4*)xp, *(const f32x4*)(xp+4), ah, al2);
        acc0[mt] = mfma3(ah, al2, wh, wl, acc0[mt]);
      }
    }
    // h1(t-1): shared A feeds Wcb (acc0) + Wh1 (acc1) -- batched
    chain8<true>(H1H_+rdo, H1L_+rdo, sWcbH, sWcbL, sWh1H, sWh1L, lane, rowA, kq, 0, acc0, acc1);
    chain8<true>(H1H_+rdo, H1L_+rdo, sWcbH, sWcbL, sWh1H, sWh1L, lane, rowA, kq, 8, acc0, acc1);
    // h0(t-1): acc0 -- batched
    chain8<false>(H0H_+rdo, H0L_+rdo, sWh0H, sWh0L, sWh0H, sWh0L, lane, rowA, kq, 0, acc0, acc1);
    chain8<false>(H0H_+rdo, H0L_+rdo, sWh0H, sWh0L, sWh0H, sWh0L, lane, rowA, kq, 8, acc0, acc1);

    // bounce C -> (row, gatecol)
    #pragma unroll
    for (int mt=0;mt<2;++mt)
      #pragma unroll
      for (int r=0;r<4;++r)
        sG[((w*2+mt)*16 + ((lane>>4)<<2) + r)*17 + l15] = acc0[mt][r];
    __syncthreads();
    {   // cell 0
      const float* gr = sG + crow*17;
      #pragma unroll
      for (int j=0;j<2;++j) {
        int d = dbase + j;
        float gi = gr[d]    + sB0[d];
        float gf = gr[4+d]  + sB0[4+d];
        float gg = gr[8+d]  + sB0[8+d];
        float go = gr[12+d] + sB0[12+d];
        c0s[j] = sigm(gf)*c0s[j] + sigm(gi)*tanhr(gg);
        float h = sigm(go)*tanhr(c0s[j]);
        bf16 hh = (bf16)h;
        sHh[crow*4+d] = hh;
        sHl[crow*4+d] = (bf16)(h - (float)hh);
      }
    }
    __syncthreads();
    if (tid < MG) {
      size_t off = wro + (size_t)(mB+tid)*H_ + ns*4;
      astore8(H0H_ + off, *(const uint2v*)(sHh + tid*4));
      astore8(H0L_ + off, *(const uint2v*)(sHl + tid*4));
    }
    group_barrier(flg, bc, ns, phase);   // A: h0(t) + out columns visible

    // ---- s(t) = s(t-1) + out(t-1); fresh Gs ----
    if (t > 0) {
      const float* SCr = SCbase + ((size_t)rd*NG + g)*(64*128);
      #pragma unroll
      for (int mt=0;mt<2;++mt) {
        int rloc = (w*2+mt)*16 + l15;
        #pragma unroll
        for (int kb=0;kb<KB_S;++kb)
          #pragma unroll
          for (int i=0;i<8;++i)
            s_reg[mt][kb*8+i] += aloadf(&SCr[(kb*32+kq+i)*128 + rloc]);
      }
    }
    #pragma unroll
    for (int mt=0;mt<2;++mt) {
      bf16x8 sh0,sl0,sh1,sl1;
      split8p(&s_reg[mt][0], sh0, sl0);
      split8p(&s_reg[mt][8], sh1, sl1);
      f32x4 a = (f32x4){0.f,0.f,0.f,0.f};
      a = mfma3(sh0, sl0, FRL(sWsH,0), FRL(sWsL,0), a);
      a = mfma3(sh1, sl1, FRL(sWsH,1), FRL(sWsL,1), a);
      Gs[mt] = a;
    }

    // ---- layer 1: acc1 += h0(t).Wi1 -- batched ----
    chain8<false>(H0H_+wro, H0L_+wro, sWi1H, sWi1L, sWi1H, sWi1L, lane, rowA, kq, 0, acc1, acc0);
    chain8<false>(H0H_+wro, H0L_+wro, sWi1H, sWi1L, sWi1H, sWi1L, lane, rowA, kq, 8, acc1, acc0);

    #pragma unroll
    for (int mt=0;mt<2;++mt)
      #pragma unroll
      for (int r=0;r<4;++r)
        sG[((w*2+mt)*16 + ((lane>>4)<<2) + r)*17 + l15] = acc1[mt][r];
    __syncthreads();
    {   // cell 1
      const float* gr = sG + crow*17;
      #pragma unroll
      for (int j=0;j<2;++j) {
        int d = dbase + j;
        float gi = gr[d]    + sB1[d];
        float gf = gr[4+d]  + sB1[4+d];
        float gg = gr[8+d]  + sB1[8+d];
        float go = gr[12+d] + sB1[12+d];
        c1s[j] = sigm(gf)*c1s[j] + sigm(gi)*tanhr(gg);
        float h = sigm(go)*tanhr(c1s[j]);
        bf16 hh = (bf16)h;
        sHh[crow*4+d] = hh;
        sHl[crow*4+d] = (bf16)(h - (float)hh);
      }
    }
    __syncthreads();
    if (tid < MG) {
      size_t off = wro + (size_t)(mB+tid)*H_ + ns*4;
      astore8(H1H_ + off, *(const uint2v*)(sHh + tid*4));
      astore8(H1L_ + off, *(const uint2v*)(sHl + tid*4));
    }
    group_barrier(flg, bc, ns, phase);   // B: h1(t) visible
  }

  // ---- epilogue: out(T-1) ----
  if ((ns & 1) == 0) {
    const bf16* hH = H1H_ + (size_t)(mB+frow)*H_ + fhalf*256;
    const bf16* hL = H1L_ + (size_t)(mB+frow)*H_ + fhalf*256;
    const float* wp = sWfc + fhalf*256;
    float a = 0.f;
    #pragma unroll
    for (int half = 0; half < 2; ++half) {
      u64 qh[16][2], ql[16][2];
      #pragma unroll
      for (int c2 = 0; c2 < 16; ++c2) {
        const u64* ph = (const u64*)(hH + half*128 + c2*8);
        const u64* pl = (const u64*)(hL + half*128 + c2*8);
        qh[c2][0] = AL(ph); qh[c2][1] = AL(ph+1);
        ql[c2][0] = AL(pl); ql[c2][1] = AL(pl+1);
      }
      #pragma unroll
      for (int c2 = 0; c2 < 16; ++c2) {
        bf16x8 hv = MK(qh[c2]), lv = MK(ql[c2]);
        const float* w2 = wp + half*128 + c2*8;
        f32x4 w0 = *(const f32x4*)w2, w1 = *(const f32x4*)(w2+4);
        a += ((float)hv[0]+(float)lv[0])*w0[0] + ((float)hv[1]+(float)lv[1])*w0[1]
           + ((float)hv[2]+(float)lv[2])*w0[2] + ((float)hv[3]+(float)lv[3])*w0[3]
           + ((float)hv[4]+(float)lv[4])*w1[0] + ((float)hv[5]+(float)lv[5])*w1[1]
           + ((float)hv[6]+(float)lv[6])*w1[2] + ((float)hv[7]+(float)lv[7])*w1[3];
      }
    }
    a += __shfl_xor(a, 1);
    if (fhalf == 0)
      out[((size_t)(mB+frow)*T_ + (T_-1))*S_ + (ns>>1)] = a + bfc_ns;
  }
}

// ---------------- launcher ----------------
extern "C" void kernel_launch(void* const* d_in, const int* in_sizes, int n_in,
                              void* d_out, int out_size, void* d_ws, size_t ws_size,
                              hipStream_t stream)
{
  const float* x   = (const float*)d_in[0];
  const float* s0  = (const float*)d_in[1];
  const float* Wi0 = (const float*)d_in[2];
  const float* Wh0 = (const float*)d_in[3];
  const float* bi0 = (const float*)d_in[4];
  const float* bh0 = (const float*)d_in[5];
  const float* Wi1 = (const float*)d_in[6];
  const float* Wh1 = (const float*)d_in[7];
  const float* bi1 = (const float*)d_in[8];
  const float* bh1 = (const float*)d_in[9];
  const float* Wfc = (const float*)d_in[10];
  const float* bfc = (const float*)d_in[11];
  float* out = (float*)d_out;
  char* ws = (char*)d_ws;

  if (ws_size < WS_NEED) return;

  hipFuncSetAttribute(reinterpret_cast<const void*>(lstm_kernel),
                      hipFuncAttributeMaxDynamicSharedMemorySize, SMEM_BYTES);

  size_t nz = 32768/16 + 4*PLANE/16;
  zero_kernel<<<(int)((nz + 255)/256), 256, 0, stream>>>(ws);
  lstm_kernel<<<NG*WPG, 256, SMEM_BYTES, stream>>>(x, s0, Wi0, Wh0, bi0, bh0,
                                                   Wi1, Wh1, bi1, bh1, Wfc, bfc,
                                                   out, ws);
}

// Round 7
// 25334.058 us; speedup vs baseline: 1.6463x; 1.6463x over previous
//
#include <hip/hip_runtime.h>
#include <cstdint>
#include <cstddef>

// ---------------- types ----------------
typedef __bf16 bf16;
typedef __bf16 bf16x8 __attribute__((ext_vector_type(8)));
typedef float  f32x4  __attribute__((ext_vector_type(4)));
typedef unsigned int uint2v __attribute__((ext_vector_type(2)));
typedef unsigned int uint4v __attribute__((ext_vector_type(4)));
typedef unsigned long long u64;

// ---------------- problem sizes ----------------
constexpr int B_=256, T_=512, H_=512, X_=128, S_=64, IN0=192;
constexpr int NG=2;              // batch groups
constexpr int MG=128;            // rows per group
constexpr int WPG=128;           // workgroups per group (slices)
constexpr int KB_X=4, KB_H=16, KB_S=2;

// ---------------- ws layout ----------------
constexpr size_t OFF_FLG=0;                           // 2*128*64 = 16384 B
constexpr size_t OFF_BC =16384;                       // 2*64 B (pad to 32768)
constexpr size_t OFF_SC =32768;                       // [2][NG][64][128] f32 = 131072 B
constexpr size_t OFF_HP =OFF_SC+2ull*NG*64*128*4;     // 4 planes: H0H,H0L,H1H,H1L
constexpr size_t PLANE  =2ull*B_*H_*2;                // 524288 B each (double buffered)
constexpr size_t WS_NEED=OFF_HP+4*PLANE;              // ~2.3 MB

// ---------------- LDS ----------------
constexpr int NWX=KB_X*512;
constexpr int NWH=KB_H*512;
constexpr int NWS=KB_S*512;
constexpr int SMEM_BYTES = (2*NWX + 8*NWH + 2*NWS)*2
                         + 512*4 + 128*17*4 + 512*2*2 + 32*4;
static_assert(SMEM_BYTES == 156288, "lds size");
static_assert(SMEM_BYTES <= 160*1024, "lds limit");

// ---------------- coherent (agent-scope, L2-bypass) access ----------------
// 16B L2-bypass load: same cache semantics as agent-scope relaxed atomic
// (compiler emits sc1 for those), but 2x fewer transactions per byte.
// Data is barrier-separated, so 16B non-atomicity is fine.
__device__ __forceinline__ uint4v ald16(const bf16* p) {
  uint4v r;
  asm volatile("global_load_dwordx4 %0, %1, off sc1"
               : "=&v"(r) : "v"(p) : "memory");
  return r;
}
__device__ __forceinline__ bf16x8 MK4(uint4v q) {
  union { uint4v q; bf16x8 v; } u; u.q = q;
  return u.v;
}
__device__ __forceinline__ void astore8(bf16* p, uint2v v) {
  union { uint2v v; u64 q; } u; u.v = v;
  __hip_atomic_store((u64*)p, u.q, __ATOMIC_RELAXED, __HIP_MEMORY_SCOPE_AGENT);
}
__device__ __forceinline__ void astoref(float* p, float v) {
  __hip_atomic_store((unsigned*)p, __float_as_uint(v), __ATOMIC_RELAXED, __HIP_MEMORY_SCOPE_AGENT);
}
__device__ __forceinline__ float aloadf(const float* p) {
  return __uint_as_float(__hip_atomic_load((unsigned*)p, __ATOMIC_RELAXED, __HIP_MEMORY_SCOPE_AGENT));
}

// ---------------- helpers ----------------
__device__ __forceinline__ f32x4 mfma16(bf16x8 a, bf16x8 b, f32x4 c) {
  return __builtin_amdgcn_mfma_f32_16x16x32_bf16(a, b, c, 0, 0, 0);
}
__device__ __forceinline__ f32x4 mfma3(bf16x8 ah, bf16x8 al, bf16x8 wh, bf16x8 wl, f32x4 c) {
  c = mfma16(ah, wh, c);
  c = mfma16(al, wh, c);
  c = mfma16(ah, wl, c);
  return c;
}
__device__ __forceinline__ void split8p(const float* v, bf16x8& ah, bf16x8& al) {
  #pragma unroll
  for (int i=0;i<8;++i){ float f=v[i]; bf16 h=(bf16)f; ah[i]=h; al[i]=(bf16)(f-(float)h); }
}
__device__ __forceinline__ void split8v(f32x4 v0, f32x4 v1, bf16x8& ah, bf16x8& al) {
  #pragma unroll
  for (int i=0;i<4;++i){ float f=v0[i]; bf16 h=(bf16)f; ah[i]=h; al[i]=(bf16)(f-(float)h); }
  #pragma unroll
  for (int i=0;i<4;++i){ float f=v1[i]; bf16 h=(bf16)f; ah[4+i]=h; al[4+i]=(bf16)(f-(float)h); }
}
__device__ __forceinline__ float sigm(float v) { return 1.0f / (1.0f + __expf(-v)); }
__device__ __forceinline__ float tanhr(float v) {
  v = fminf(15.0f, fmaxf(-15.0f, v));
  float e = __expf(2.0f * v);
  return (e - 1.0f) / (e + 1.0f);
}

// Fence-free group barrier (R5, unchanged)
__device__ __forceinline__ void group_barrier(int* flg, int* bc, int ns, int& phase) {
  ++phase;
  const int p = phase;
  asm volatile("s_waitcnt vmcnt(0)" ::: "memory");
  __syncthreads();
  if (threadIdx.x == 0)
    __hip_atomic_store(flg + ns*16, p, __ATOMIC_RELAXED, __HIP_MEMORY_SCOPE_AGENT);
  if (ns == 0) {
    if (threadIdx.x < WPG) {
      while (__hip_atomic_load(flg + (int)threadIdx.x*16, __ATOMIC_RELAXED,
                               __HIP_MEMORY_SCOPE_AGENT) < p)
        __builtin_amdgcn_s_sleep(1);
    }
    __syncthreads();
    if (threadIdx.x == 0)
      __hip_atomic_store(bc, p, __ATOMIC_RELAXED, __HIP_MEMORY_SCOPE_AGENT);
  }
  if (threadIdx.x == 0) {
    while (__hip_atomic_load(bc, __ATOMIC_RELAXED, __HIP_MEMORY_SCOPE_AGENT) < p)
      __builtin_amdgcn_s_sleep(1);
  }
  __syncthreads();
}

__device__ void pack_slice(bf16* dH, bf16* dL, const float* src, int stride,
                           int koff, int nkb, int ns) {
  for (int p = (int)threadIdx.x; p < nkb*64; p += 256) {
    int ln = p & 63, kb = p >> 6;
    int c = ln & 15, k = kb*32 + ((ln>>4)<<3);
    int gcol = ((c>>2)<<9) + ns*4 + (c&3);
    const float* sp = src + (size_t)gcol*stride + koff + k;
    f32x4 v0 = *(const f32x4*)sp, v1 = *(const f32x4*)(sp+4);
    bf16x8 hv, lv;
    split8v(v0, v1, hv, lv);
    *(bf16x8*)(dH + p*8) = hv;
    *(bf16x8*)(dL + p*8) = lv;
  }
}

// ---------------- zero kernel ----------------
__global__ void zero_kernel(char* __restrict__ ws) {
  size_t i = (size_t)blockIdx.x*256 + threadIdx.x;
  size_t nsync = 32768/16;
  if (i < nsync) { ((uint4v*)(ws+OFF_FLG))[i] = (uint4v){0,0,0,0}; return; }
  i -= nsync;
  if (i < 4*PLANE/16) ((uint4v*)(ws+OFF_HP))[i] = (uint4v){0,0,0,0};
}

// ---------------- persistent LSTM kernel ----------------
#define FRL(base, kb) (*(const bf16x8*)((base) + (((kb)*64 + lane)*8)))

// Batched half-chain: issue 32 x 16B sc1 loads (2 mt x 8 kb x {hi,lo}),
// waitcnt + sched_barrier, then consume with MFMAs.
template<bool DUAL>
__device__ __forceinline__ void chain8(const bf16* pH, const bf16* pL,
    const bf16* sWH, const bf16* sWL, const bf16* sW2H, const bf16* sW2L,
    int lane, const int* rowA, int kq, int kb0, f32x4* accA, f32x4* accB)
{
  uint4v qh[2][8], ql[2][8];
  #pragma unroll
  for (int mt=0;mt<2;++mt) {
    const bf16* bH = pH + (size_t)rowA[mt]*H_ + kb0*32 + kq;
    const bf16* bL = pL + (size_t)rowA[mt]*H_ + kb0*32 + kq;
    #pragma unroll
    for (int k=0;k<8;++k) {
      qh[mt][k] = ald16(bH + k*32);
      ql[mt][k] = ald16(bL + k*32);
    }
  }
  asm volatile("s_waitcnt vmcnt(0)" ::: "memory");
  __builtin_amdgcn_sched_barrier(0);
  #pragma unroll
  for (int k=0;k<8;++k) {
    const int kb = kb0 + k;
    bf16x8 wh = FRL(sWH,kb), wl = FRL(sWL,kb);
    #pragma unroll
    for (int mt=0;mt<2;++mt) {
      bf16x8 ah = MK4(qh[mt][k]), al2 = MK4(ql[mt][k]);
      accA[mt] = mfma3(ah, al2, wh, wl, accA[mt]);
      if (DUAL) {
        bf16x8 w2h = FRL(sW2H,kb), w2l = FRL(sW2L,kb);
        accB[mt] = mfma3(ah, al2, w2h, w2l, accB[mt]);
      }
    }
  }
}

// fc half-row dot: 32 x 16B sc1 loads then fp32 dot with LDS weights
__device__ __forceinline__ float fc_half(const bf16* hH, const bf16* hL,
                                         const float* wp)
{
  float a = 0.f;
  #pragma unroll
  for (int half = 0; half < 2; ++half) {
    uint4v qh[16], ql[16];
    #pragma unroll
    for (int c2 = 0; c2 < 16; ++c2) {
      qh[c2] = ald16(hH + half*128 + c2*8);
      ql[c2] = ald16(hL + half*128 + c2*8);
    }
    asm volatile("s_waitcnt vmcnt(0)" ::: "memory");
    __builtin_amdgcn_sched_barrier(0);
    #pragma unroll
    for (int c2 = 0; c2 < 16; ++c2) {
      bf16x8 hv = MK4(qh[c2]), lv = MK4(ql[c2]);
      const float* w2 = wp + half*128 + c2*8;
      f32x4 w0 = *(const f32x4*)w2, w1 = *(const f32x4*)(w2+4);
      a += ((float)hv[0]+(float)lv[0])*w0[0] + ((float)hv[1]+(float)lv[1])*w0[1]
         + ((float)hv[2]+(float)lv[2])*w0[2] + ((float)hv[3]+(float)lv[3])*w0[3]
         + ((float)hv[4]+(float)lv[4])*w1[0] + ((float)hv[5]+(float)lv[5])*w1[1]
         + ((float)hv[6]+(float)lv[6])*w1[2] + ((float)hv[7]+(float)lv[7])*w1[3];
    }
  }
  return a;
}

__global__ void __launch_bounds__(256, 1)
lstm_kernel(const float* __restrict__ x, const float* __restrict__ s0,
            const float* __restrict__ Wi0, const float* __restrict__ Wh0g,
            const float* __restrict__ bi0, const float* __restrict__ bh0,
            const float* __restrict__ Wi1g, const float* __restrict__ Wh1g,
            const float* __restrict__ bi1, const float* __restrict__ bh1,
            const float* __restrict__ Wfc, const float* __restrict__ bfc,
            float* __restrict__ out, char* __restrict__ ws)
{
  const int bid = blockIdx.x;
  const int g = bid & 1, ns = bid >> 1;
  const int tid = threadIdx.x;
  const int w = tid >> 6, lane = tid & 63, l15 = lane & 15;
  const int kq = (lane >> 4) << 3;
  const int mB = g * MG;
  int rowA[2];
  rowA[0] = mB + (w*2)*16 + l15;
  rowA[1] = rowA[0] + 16;

  int* flg = (int*)(ws + OFF_FLG) + g*128*16;
  int* bc  = (int*)(ws + OFF_BC) + g*16;
  float* SCbase = (float*)(ws + OFF_SC);
  bf16* H0H_ = (bf16*)(ws + OFF_HP);
  bf16* H0L_ = (bf16*)(ws + OFF_HP + PLANE);
  bf16* H1H_ = (bf16*)(ws + OFF_HP + 2*PLANE);
  bf16* H1L_ = (bf16*)(ws + OFF_HP + 3*PLANE);

  extern __shared__ char smem[];
  bf16* sWxH  = (bf16*)smem;
  bf16* sWxL  = sWxH + NWX;
  bf16* sWh0H = sWxL + NWX;
  bf16* sWh0L = sWh0H + NWH;
  bf16* sWcbH = sWh0L + NWH;
  bf16* sWcbL = sWcbH + NWH;
  bf16* sWi1H = sWcbL + NWH;
  bf16* sWi1L = sWi1H + NWH;
  bf16* sWh1H = sWi1L + NWH;
  bf16* sWh1L = sWh1H + NWH;
  bf16* sWsH  = sWh1L + NWH;
  bf16* sWsL  = sWsH + NWS;
  float* sWfc = (float*)(sWsL + NWS);
  float* sG   = sWfc + 512;
  bf16*  sHh  = (bf16*)(sG + 128*17);
  bf16*  sHl  = sHh + 512;
  float* sB0  = (float*)(sHl + 512);
  float* sB1  = sB0 + 16;

  // ---- in-kernel weight packing (hi/lo bf16 pairs) ----
  pack_slice(sWxH,  sWxL,  Wi0,  IN0, 0,  KB_X, ns);
  pack_slice(sWh0H, sWh0L, Wh0g, H_,  0,  KB_H, ns);
  pack_slice(sWi1H, sWi1L, Wi1g, H_,  0,  KB_H, ns);
  pack_slice(sWh1H, sWh1L, Wh1g, H_,  0,  KB_H, ns);
  pack_slice(sWsH,  sWsL,  Wi0,  IN0, X_, KB_S, ns);
  for (int p = tid; p < KB_H*64; p += 256) {
    int ln = p & 63, kb = p >> 6;
    int c = ln & 15, k = kb*32 + ((ln>>4)<<3);
    int gcol = ((c>>2)<<9) + ns*4 + (c&3);
    const float* wis = Wi0 + (size_t)gcol*IN0 + X_;
    float a[8] = {0,0,0,0,0,0,0,0};
    for (int o = 0; o < S_; ++o) {
      float wv = wis[o];
      const float* fr = Wfc + (size_t)o*H_ + k;
      f32x4 f0 = *(const f32x4*)fr, f1 = *(const f32x4*)(fr+4);
      a[0]+=wv*f0[0]; a[1]+=wv*f0[1]; a[2]+=wv*f0[2]; a[3]+=wv*f0[3];
      a[4]+=wv*f1[0]; a[5]+=wv*f1[1]; a[6]+=wv*f1[2]; a[7]+=wv*f1[3];
    }
    bf16x8 hv, lv;
    split8p(a, hv, lv);
    *(bf16x8*)(sWcbH + p*8) = hv;
    *(bf16x8*)(sWcbL + p*8) = lv;
  }
  for (int j = tid; j < H_; j += 256) sWfc[j] = Wfc[(size_t)(ns>>1)*H_ + j];
  if (tid < 16) {
    int gcol = ((tid>>2)<<9) + ns*4 + (tid&3);
    sB0[tid] = bi0[gcol] + bh0[gcol];
    sB1[tid] = bi1[gcol] + bh1[gcol];
  }

  float bfcW;
  {
    int gcol = ((l15>>2)<<9) + ns*4 + (l15&3);
    const float* wr = Wi0 + (size_t)gcol*IN0 + X_;
    float bw = 0.f;
    for (int o = 0; o < S_; ++o) bw += bfc[o]*wr[o];
    bfcW = bw;
  }
  const float bfc_ns = bfc[ns>>1];

  float s_reg[2][16];
  #pragma unroll
  for (int mt=0;mt<2;++mt)
    #pragma unroll
    for (int kb=0;kb<KB_S;++kb)
      #pragma unroll
      for (int i=0;i<8;++i)
        s_reg[mt][kb*8+i] = s0[(size_t)rowA[mt]*S_ + kb*32 + kq + i];

  __syncthreads();

  f32x4 Gs[2];
  #pragma unroll
  for (int mt=0;mt<2;++mt) {
    bf16x8 sh0,sl0,sh1,sl1;
    split8p(&s_reg[mt][0], sh0, sl0);
    split8p(&s_reg[mt][8], sh1, sl1);
    f32x4 a = (f32x4){0.f,0.f,0.f,0.f};
    a = mfma3(sh0, sl0, FRL(sWsH,0), FRL(sWsL,0), a);
    a = mfma3(sh1, sl1, FRL(sWsH,1), FRL(sWsL,1), a);
    Gs[mt] = a;
  }

  float c0s[2] = {0.f,0.f}, c1s[2] = {0.f,0.f};
  const int crow = tid >> 1;
  const int dbase = (tid & 1) << 1;
  const int frow = tid >> 1, fhalf = tid & 1;
  int phase = 0;

  for (int t = 0; t < T_; ++t) {
    const int rd = t & 1, wr = rd ^ 1;
    const size_t rdo = (size_t)rd*B_*H_, wro = (size_t)wr*B_*H_;
    float* SCp = SCbase + ((size_t)rd*NG + g)*(64*128);

    // ---- fc (fp32, even slices): out(t-1)[:, ns>>1] ----
    if (t > 0 && (ns & 1) == 0) {
      const bf16* hH = H1H_ + rdo + (size_t)(mB+frow)*H_ + fhalf*256;
      const bf16* hL = H1L_ + rdo + (size_t)(mB+frow)*H_ + fhalf*256;
      float a = fc_half(hH, hL, sWfc + fhalf*256);
      a += __shfl_xor(a, 1);
      if (fhalf == 0) {
        float o = a + bfc_ns;
        out[((size_t)(mB+frow)*T_ + (t-1))*S_ + (ns>>1)] = o;
        astoref(&SCp[(ns>>1)*128 + frow], o);
      }
    }

    // ---- phase-1 MFMA ----
    f32x4 acc0[2], acc1[2];
    {
      float addb = (t > 0) ? bfcW : 0.f;
      #pragma unroll
      for (int mt=0;mt<2;++mt) {
        #pragma unroll
        for (int r=0;r<4;++r) acc0[mt][r] = Gs[mt][r] + addb;
        acc1[mt] = (f32x4){0.f,0.f,0.f,0.f};
      }
    }
    #pragma unroll
    for (int kb=0; kb<KB_X; ++kb) {          // x chain (cached loads)
      bf16x8 wh = FRL(sWxH,kb), wl = FRL(sWxL,kb);
      #pragma unroll
      for (int mt=0;mt<2;++mt) {
        const float* xp = x + ((size_t)rowA[mt]*T_ + t)*X_ + kb*32 + kq;
        bf16x8 ah, al2;
        split8v(*(const f32x4*)xp, *(const f32x4*)(xp+4), ah, al2);
        acc0[mt] = mfma3(ah, al2, wh, wl, acc0[mt]);
      }
    }
    // h1(t-1): shared A feeds Wcb (acc0) + Wh1 (acc1)
    chain8<true>(H1H_+rdo, H1L_+rdo, sWcbH, sWcbL, sWh1H, sWh1L, lane, rowA, kq, 0, acc0, acc1);
    chain8<true>(H1H_+rdo, H1L_+rdo, sWcbH, sWcbL, sWh1H, sWh1L, lane, rowA, kq, 8, acc0, acc1);
    // h0(t-1): acc0
    chain8<false>(H0H_+rdo, H0L_+rdo, sWh0H, sWh0L, sWh0H, sWh0L, lane, rowA, kq, 0, acc0, acc1);
    chain8<false>(H0H_+rdo, H0L_+rdo, sWh0H, sWh0L, sWh0H, sWh0L, lane, rowA, kq, 8, acc0, acc1);

    // bounce C -> (row, gatecol)
    #pragma unroll
    for (int mt=0;mt<2;++mt)
      #pragma unroll
      for (int r=0;r<4;++r)
        sG[((w*2+mt)*16 + ((lane>>4)<<2) + r)*17 + l15] = acc0[mt][r];
    __syncthreads();
    {   // cell 0
      const float* gr = sG + crow*17;
      #pragma unroll
      for (int j=0;j<2;++j) {
        int d = dbase + j;
        float gi = gr[d]    + sB0[d];
        float gf = gr[4+d]  + sB0[4+d];
        float gg = gr[8+d]  + sB0[8+d];
        float go = gr[12+d] + sB0[12+d];
        c0s[j] = sigm(gf)*c0s[j] + sigm(gi)*tanhr(gg);
        float h = sigm(go)*tanhr(c0s[j]);
        bf16 hh = (bf16)h;
        sHh[crow*4+d] = hh;
        sHl[crow*4+d] = (bf16)(h - (float)hh);
      }
    }
    __syncthreads();
    if (tid < MG) {
      size_t off = wro + (size_t)(mB+tid)*H_ + ns*4;
      astore8(H0H_ + off, *(const uint2v*)(sHh + tid*4));
      astore8(H0L_ + off, *(const uint2v*)(sHl + tid*4));
    }
    group_barrier(flg, bc, ns, phase);   // A: h0(t) + out columns visible

    // ---- s(t) = s(t-1) + out(t-1); fresh Gs ----
    if (t > 0) {
      const float* SCr = SCbase + ((size_t)rd*NG + g)*(64*128);
      #pragma unroll
      for (int mt=0;mt<2;++mt) {
        int rloc = (w*2+mt)*16 + l15;
        #pragma unroll
        for (int kb=0;kb<KB_S;++kb)
          #pragma unroll
          for (int i=0;i<8;++i)
            s_reg[mt][kb*8+i] += aloadf(&SCr[(kb*32+kq+i)*128 + rloc]);
      }
    }
    #pragma unroll
    for (int mt=0;mt<2;++mt) {
      bf16x8 sh0,sl0,sh1,sl1;
      split8p(&s_reg[mt][0], sh0, sl0);
      split8p(&s_reg[mt][8], sh1, sl1);
      f32x4 a = (f32x4){0.f,0.f,0.f,0.f};
      a = mfma3(sh0, sl0, FRL(sWsH,0), FRL(sWsL,0), a);
      a = mfma3(sh1, sl1, FRL(sWsH,1), FRL(sWsL,1), a);
      Gs[mt] = a;
    }

    // ---- layer 1: acc1 += h0(t).Wi1 ----
    chain8<false>(H0H_+wro, H0L_+wro, sWi1H, sWi1L, sWi1H, sWi1L, lane, rowA, kq, 0, acc1, acc0);
    chain8<false>(H0H_+wro, H0L_+wro, sWi1H, sWi1L, sWi1H, sWi1L, lane, rowA, kq, 8, acc1, acc0);

    #pragma unroll
    for (int mt=0;mt<2;++mt)
      #pragma unroll
      for (int r=0;r<4;++r)
        sG[((w*2+mt)*16 + ((lane>>4)<<2) + r)*17 + l15] = acc1[mt][r];
    __syncthreads();
    {   // cell 1
      const float* gr = sG + crow*17;
      #pragma unroll
      for (int j=0;j<2;++j) {
        int d = dbase + j;
        float gi = gr[d]    + sB1[d];
        float gf = gr[4+d]  + sB1[4+d];
        float gg = gr[8+d]  + sB1[8+d];
        float go = gr[12+d] + sB1[12+d];
        c1s[j] = sigm(gf)*c1s[j] + sigm(gi)*tanhr(gg);
        float h = sigm(go)*tanhr(c1s[j]);
        bf16 hh = (bf16)h;
        sHh[crow*4+d] = hh;
        sHl[crow*4+d] = (bf16)(h - (float)hh);
      }
    }
    __syncthreads();
    if (tid < MG) {
      size_t off = wro + (size_t)(mB+tid)*H_ + ns*4;
      astore8(H1H_ + off, *(const uint2v*)(sHh + tid*4));
      astore8(H1L_ + off, *(const uint2v*)(sHl + tid*4));
    }
    group_barrier(flg, bc, ns, phase);   // B: h1(t) visible
  }

  // ---- epilogue: out(T-1) ----
  if ((ns & 1) == 0) {
    const bf16* hH = H1H_ + (size_t)(mB+frow)*H_ + fhalf*256;
    const bf16* hL = H1L_ + (size_t)(mB+frow)*H_ + fhalf*256;
    float a = fc_half(hH, hL, sWfc + fhalf*256);
    a += __shfl_xor(a, 1);
    if (fhalf == 0)
      out[((size_t)(mB+frow)*T_ + (T_-1))*S_ + (ns>>1)] = a + bfc_ns;
  }
}

// ---------------- launcher ----------------
extern "C" void kernel_launch(void* const* d_in, const int* in_sizes, int n_in,
                              void* d_out, int out_size, void* d_ws, size_t ws_size,
                              hipStream_t stream)
{
  const float* x   = (const float*)d_in[0];
  const float* s0  = (const float*)d_in[1];
  const float* Wi0 = (const float*)d_in[2];
  const float* Wh0 = (const float*)d_in[3];
  const float* bi0 = (const float*)d_in[4];
  const float* bh0 = (const float*)d_in[5];
  const float* Wi1 = (const float*)d_in[6];
  const float* Wh1 = (const float*)d_in[7];
  const float* bi1 = (const float*)d_in[8];
  const float* bh1 = (const float*)d_in[9];
  const float* Wfc = (const float*)d_in[10];
  const float* bfc = (const float*)d_in[11];
  float* out = (float*)d_out;
  char* ws = (char*)d_ws;

  if (ws_size < WS_NEED) return;

  hipFuncSetAttribute(reinterpret_cast<const void*>(lstm_kernel),
                      hipFuncAttributeMaxDynamicSharedMemorySize, SMEM_BYTES);

  size_t nz = 32768/16 + 4*PLANE/16;
  zero_kernel<<<(int)((nz + 255)/256), 256, 0, stream>>>(ws);
  lstm_kernel<<<NG*WPG, 256, SMEM_BYTES, stream>>>(x, s0, Wi0, Wh0, bi0, bh0,
                                                   Wi1, Wh1, bi1, bh1, Wfc, bfc,
                                                   out, ws);
}